// Round 8
// baseline (1751.358 us; speedup 1.0000x reference)
//
#include <hip/hip_runtime.h>
#include <math.h>

#define IGNORE_INDEX (-100)

typedef __attribute__((ext_vector_type(4))) int i32x4;
typedef __attribute__((ext_vector_type(4))) float f32x4;

static constexpr int B_ = 4, S_ = 2048, H_ = 4096, V_ = 32000;
static constexpr int N_ = B_ * (S_ - 1);      // 8188 rows after causal shift
static constexpr int NPAD = 8192;             // padded rows
static constexpr int BM = 256, BN = 256, BK = 128;
static constexpr int NVB = V_ / BN;           // 125 v-blocks
static constexpr int NRB = NPAD / BM;         // 32 row-blocks
static constexpr int NKT = H_ / BK;           // 32 K-tiles
static constexpr int NWG = NVB * NRB;         // 4000 blocks

__device__ __forceinline__ void gload16(const signed char* src, signed char* ldst) {
    __builtin_amdgcn_global_load_lds(
        (const __attribute__((address_space(1))) unsigned int*)src,
        (__attribute__((address_space(3))) unsigned int*)ldst, 16, 0, 0);
}

// ---------- per-row symmetric int8 quantization of hidden_states (causal-shifted, padded) ----------
__global__ void quant_hs_kernel(const float* __restrict__ hs,
                                signed char* __restrict__ qA, float* __restrict__ sA) {
    const int row = blockIdx.x;          // 0..NPAD-1
    const int tid = threadIdx.x;         // 256 threads
    __shared__ float red[256];
    f32x4 v0, v1, v2, v3;
    if (row < N_) {
        int b = row / (S_ - 1);
        int s = row - b * (S_ - 1);
        const float* src = hs + (size_t)(b * S_ + s) * H_;
        v0 = *(const f32x4*)(src + tid * 4 + 0 * 1024);
        v1 = *(const f32x4*)(src + tid * 4 + 1 * 1024);
        v2 = *(const f32x4*)(src + tid * 4 + 2 * 1024);
        v3 = *(const f32x4*)(src + tid * 4 + 3 * 1024);
    } else {
        v0 = v1 = v2 = v3 = (f32x4)0.f;
    }
    float amax = 0.f;
    amax = fmaxf(amax, fmaxf(fmaxf(fabsf(v0[0]), fabsf(v0[1])), fmaxf(fabsf(v0[2]), fabsf(v0[3]))));
    amax = fmaxf(amax, fmaxf(fmaxf(fabsf(v1[0]), fabsf(v1[1])), fmaxf(fabsf(v1[2]), fabsf(v1[3]))));
    amax = fmaxf(amax, fmaxf(fmaxf(fabsf(v2[0]), fabsf(v2[1])), fmaxf(fabsf(v2[2]), fabsf(v2[3]))));
    amax = fmaxf(amax, fmaxf(fmaxf(fabsf(v3[0]), fabsf(v3[1])), fmaxf(fabsf(v3[2]), fabsf(v3[3]))));
    red[tid] = amax;
    __syncthreads();
    for (int d = 128; d > 0; d >>= 1) {
        if (tid < d) red[tid] = fmaxf(red[tid], red[tid + d]);
        __syncthreads();
    }
    const float m = fmaxf(red[0], 1e-30f);
    const float inv = 127.f / m;
    unsigned int* dst = (unsigned int*)(qA + (size_t)row * H_);
#define QPACK(vv, J) do { \
    int q0 = __float2int_rn(vv[0] * inv), q1 = __float2int_rn(vv[1] * inv); \
    int q2 = __float2int_rn(vv[2] * inv), q3 = __float2int_rn(vv[3] * inv); \
    unsigned int p = (q0 & 255) | ((q1 & 255) << 8) | ((q2 & 255) << 16) | ((unsigned)(q3 & 255) << 24); \
    dst[tid + (J) * 256] = p; } while (0)
    QPACK(v0, 0); QPACK(v1, 1); QPACK(v2, 2); QPACK(v3, 3);
#undef QPACK
    if (tid == 0) sA[row] = m * (1.f / 127.f);
}

// ---------- per-row symmetric int8 quantization of lm_head weight ----------
__global__ void quant_w_kernel(const float* __restrict__ w,
                               signed char* __restrict__ qW, float* __restrict__ sW) {
    const int row = blockIdx.x;          // 0..V-1
    const int tid = threadIdx.x;
    __shared__ float red[256];
    const float* src = w + (size_t)row * H_;
    f32x4 v0 = *(const f32x4*)(src + tid * 4 + 0 * 1024);
    f32x4 v1 = *(const f32x4*)(src + tid * 4 + 1 * 1024);
    f32x4 v2 = *(const f32x4*)(src + tid * 4 + 2 * 1024);
    f32x4 v3 = *(const f32x4*)(src + tid * 4 + 3 * 1024);
    float amax = 0.f;
    amax = fmaxf(amax, fmaxf(fmaxf(fabsf(v0[0]), fabsf(v0[1])), fmaxf(fabsf(v0[2]), fabsf(v0[3]))));
    amax = fmaxf(amax, fmaxf(fmaxf(fabsf(v1[0]), fabsf(v1[1])), fmaxf(fabsf(v1[2]), fabsf(v1[3]))));
    amax = fmaxf(amax, fmaxf(fmaxf(fabsf(v2[0]), fabsf(v2[1])), fmaxf(fabsf(v2[2]), fabsf(v2[3]))));
    amax = fmaxf(amax, fmaxf(fmaxf(fabsf(v3[0]), fabsf(v3[1])), fmaxf(fabsf(v3[2]), fabsf(v3[3]))));
    red[tid] = amax;
    __syncthreads();
    for (int d = 128; d > 0; d >>= 1) {
        if (tid < d) red[tid] = fmaxf(red[tid], red[tid + d]);
        __syncthreads();
    }
    const float m = fmaxf(red[0], 1e-30f);
    const float inv = 127.f / m;
    unsigned int* dst = (unsigned int*)(qW + (size_t)row * H_);
#define QPACK(vv, J) do { \
    int q0 = __float2int_rn(vv[0] * inv), q1 = __float2int_rn(vv[1] * inv); \
    int q2 = __float2int_rn(vv[2] * inv), q3 = __float2int_rn(vv[3] * inv); \
    unsigned int p = (q0 & 255) | ((q1 & 255) << 8) | ((q2 & 255) << 16) | ((unsigned)(q3 & 255) << 24); \
    dst[tid + (J) * 256] = p; } while (0)
    QPACK(v0, 0); QPACK(v1, 1); QPACK(v2, 2); QPACK(v3, 3);
#undef QPACK
    if (tid == 0) sW[row] = m * (1.f / 127.f);
}

// ---------- 256x256 8-wave i8 GEMM (BK=128), register-dbuf pipelined, fused partial LSE ----------
// LDS layout identical to R7 (verified 0 bank conflicts): [256 rows][128 cols] i8,
// physical byte = r*128 + ((slot*16) ^ ((r&7)<<4)); kk half-step = phys^64; staging source
// inverse-swizzled.  NEW this round: the K-tile interior is 4 MFMA clusters with ds_reads
// rolled ONE CLUSTER AHEAD into registers (counted lgkmcnt, m201/T4 pattern at reg level):
//   issue c0(8), c1(4) | lgkm(4) MFMA c0 | issue c2(8) lgkm(8) MFMA c1 |
//   issue c3(4) lgkm(4) MFMA c2 | lgkm(0) MFMA c3 | vmcnt(0) barrier
// -> cluster k+1's read completion hides under cluster k's MFMA; 1 barrier/tile (was 8).
// sched_barrier(0) pins read-group boundaries so the counted lgkmcnt N stays exact (rule 18).
// Peak live fragments ~16 (64 VGPR) + acc in AGPR(128): ~240 total, fits 2 waves/SIMD.
__global__ __launch_bounds__(512, 2) void gemm_lse_kernel(
        const signed char* __restrict__ Aq,    // [NPAD][H] i8
        const signed char* __restrict__ Wq,    // [V][H] i8
        const float* __restrict__ sA,          // [NPAD]
        const float* __restrict__ sW,          // [V]
        const int* __restrict__ labels,        // [B][S]
        float* __restrict__ partial_m,         // [NPAD][NVB]
        float* __restrict__ partial_s,         // [NPAD][NVB]
        float* __restrict__ label_logit)       // [NPAD]
{
    __shared__ signed char lds[2][2][BM * BK];   // [buf][A=0/B=1], 2 x 64 KiB = 128 KiB

    const int tid  = threadIdx.x;
    const int lane = tid & 63;
    const int wid  = tid >> 6;
    const int wr   = wid >> 2;      // 0..1: row half
    const int wc   = wid & 3;       // 0..3: col quarter
    const int lq   = lane & 15;
    const int lr   = lane >> 4;

    // bijective XCD swizzle (NWG % 8 == 0)
    int lin = blockIdx.x;
    int swz = (lin & 7) * (NWG / 8) + (lin >> 3);
    const int rb = swz / NVB;
    const int vb = swz - rb * NVB;

    const signed char* Abase = Aq + (size_t)rb * BM * H_;
    const signed char* Bbase = Wq + (size_t)vb * BN * H_;

    // ds_read physical byte offsets for kk=0 (kk=1 is offset ^ 64)
    int pA[8], pB[4];
    #pragma unroll
    for (int m = 0; m < 8; ++m) {
        int r = wr * 128 + m * 16 + lq;
        pA[m] = r * 128 + ((lr * 16) ^ ((r & 7) << 4));
    }
    #pragma unroll
    for (int n = 0; n < 4; ++n) {
        int r = wc * 64 + n * 16 + lq;
        pB[n] = r * 128 + ((lr * 16) ^ ((r & 7) << 4));
    }

    // staging: linear physical dest (gload_lds = base + lane*16); inverse-swizzled source.
    int rowS[4], colS[4];
    #pragma unroll
    for (int i = 0; i < 4; ++i) {
        int q = i * 8192 + wid * 1024 + lane * 16;   // physical
        int b = q ^ (((q >> 7) & 7) << 4);           // logical
        rowS[i] = b >> 7;
        colS[i] = b & 127;                           // i8: byte == element
    }

    i32x4 acc[8][4] = {};

    // ---------- prologue: stage K-tile 0 into buf 0 ----------
    {
        signed char* dA = &lds[0][0][0];
        signed char* dB = &lds[0][1][0];
        #pragma unroll
        for (int i = 0; i < 4; ++i)
            gload16(Abase + (size_t)rowS[i] * H_ + colS[i], dA + i * 8192 + wid * 1024);
        #pragma unroll
        for (int i = 0; i < 4; ++i)
            gload16(Bbase + (size_t)rowS[i] * H_ + colS[i], dB + i * 8192 + wid * 1024);
    }
    asm volatile("s_waitcnt vmcnt(0)" ::: "memory");
    __builtin_amdgcn_s_barrier();

#define RDI(tile, off) (*(const volatile i32x4*)((const char*)(tile) + (off)))
#define MF(af, bf, c4) __builtin_amdgcn_mfma_i32_16x16x64_i8(af, bf, c4, 0, 0, 0)
#define SB() __builtin_amdgcn_sched_barrier(0)
#define WAITL(N) do { asm volatile("s_waitcnt lgkmcnt(" #N ")" ::: "memory"); SB(); } while (0)

    for (int T = 0; T < NKT; ++T) {
        const int cur = T & 1;
        const signed char* tA = &lds[cur][0][0];
        const signed char* tB = &lds[cur][1][0];
        signed char* dA = &lds[cur ^ 1][0][0];
        signed char* dB = &lds[cur ^ 1][1][0];
        const int kn = (T + 1) * BK;
        const bool pre = (T + 1 < NKT);

        // ---- issue ALL stage gloads for T+1 (full-tile HBM cover before the boundary drain)
        if (pre) {
            #pragma unroll
            for (int i = 0; i < 4; ++i)
                gload16(Abase + (size_t)rowS[i] * H_ + kn + colS[i], dA + i * 8192 + wid * 1024);
            #pragma unroll
            for (int i = 0; i < 4; ++i)
                gload16(Bbase + (size_t)rowS[i] * H_ + kn + colS[i], dB + i * 8192 + wid * 1024);
        }

        i32x4 fA0[8], fB0[4], fA1[8], fB1[4];

        // ---- c0 reads: A kk0 m0-3 + B kk0 (8)
        #pragma unroll
        for (int m = 0; m < 4; ++m) fA0[m] = RDI(tA, pA[m]);
        #pragma unroll
        for (int n = 0; n < 4; ++n) fB0[n] = RDI(tB, pB[n]);
        SB();
        // ---- c1 reads: A kk0 m4-7 (4)
        #pragma unroll
        for (int m = 4; m < 8; ++m) fA0[m] = RDI(tA, pA[m]);
        SB();
        WAITL(4);                       // c0 landed; c1 in flight
        __builtin_amdgcn_s_setprio(1);
        #pragma unroll
        for (int m = 0; m < 4; ++m)
            #pragma unroll
            for (int n = 0; n < 4; ++n)
                acc[m][n] = MF(fA0[m], fB0[n], acc[m][n]);
        __builtin_amdgcn_s_setprio(0);
        SB();
        // ---- c2 reads: A kk1 m0-3 + B kk1 (8)
        #pragma unroll
        for (int m = 0; m < 4; ++m) fA1[m] = RDI(tA, pA[m] ^ 64);
        #pragma unroll
        for (int n = 0; n < 4; ++n) fB1[n] = RDI(tB, pB[n] ^ 64);
        SB();
        WAITL(8);                       // c1 landed; c2 in flight
        __builtin_amdgcn_s_setprio(1);
        #pragma unroll
        for (int m = 0; m < 4; ++m)
            #pragma unroll
            for (int n = 0; n < 4; ++n)
                acc[4 + m][n] = MF(fA0[4 + m], fB0[n], acc[4 + m][n]);
        __builtin_amdgcn_s_setprio(0);
        SB();
        // ---- c3 reads: A kk1 m4-7 (4)
        #pragma unroll
        for (int m = 4; m < 8; ++m) fA1[m] = RDI(tA, pA[m] ^ 64);
        SB();
        WAITL(4);                       // c2 landed; c3 in flight
        __builtin_amdgcn_s_setprio(1);
        #pragma unroll
        for (int m = 0; m < 4; ++m)
            #pragma unroll
            for (int n = 0; n < 4; ++n)
                acc[m][n] = MF(fA1[m], fB1[n], acc[m][n]);
        __builtin_amdgcn_s_setprio(0);
        SB();
        WAITL(0);                       // c3 landed
        __builtin_amdgcn_s_setprio(1);
        #pragma unroll
        for (int m = 0; m < 4; ++m)
            #pragma unroll
            for (int n = 0; n < 4; ++n)
                acc[4 + m][n] = MF(fA1[4 + m], fB1[n], acc[4 + m][n]);
        __builtin_amdgcn_s_setprio(0);
        SB();
        // ---- tile boundary: stages for T+1 were issued a full tile ago -> near-free drain
        asm volatile("s_waitcnt vmcnt(0)" ::: "memory");
        __builtin_amdgcn_s_barrier();
    }

    // ---------- epilogue: dequant + per-row max & sum-exp over this 256-col tile ----------
    __syncthreads();
    float* red_m = (float*)&lds[0][0][0];   // [4][256]
    float* red_s = red_m + 1024;            // [4][256]

    const float* sArow = sA + rb * 256 + wr * 128;
    const float sw0 = sW[vb * 256 + wc * 64 + 0 * 16 + lq];
    const float sw1 = sW[vb * 256 + wc * 64 + 1 * 16 + lq];
    const float sw2 = sW[vb * 256 + wc * 64 + 2 * 16 + lq];
    const float sw3 = sW[vb * 256 + wc * 64 + 3 * 16 + lq];

    #pragma unroll
    for (int m = 0; m < 8; ++m) {
        f32x4 sav = *(const f32x4*)(sArow + m * 16 + lr * 4);
        #pragma unroll
        for (int q = 0; q < 4; ++q) {
            const float sa = sav[q];
            float l0 = (float)acc[m][0][q] * sa * sw0;
            float l1 = (float)acc[m][1][q] * sa * sw1;
            float l2 = (float)acc[m][2][q] * sa * sw2;
            float l3 = (float)acc[m][3][q] * sa * sw3;
            float mx = fmaxf(fmaxf(l0, l1), fmaxf(l2, l3));
            #pragma unroll
            for (int d = 1; d < 16; d <<= 1) mx = fmaxf(mx, __shfl_xor(mx, d, 64));
            float ss = __expf(l0 - mx) + __expf(l1 - mx) + __expf(l2 - mx) + __expf(l3 - mx);
            #pragma unroll
            for (int d = 1; d < 16; d <<= 1) ss += __shfl_xor(ss, d, 64);
            if (lq == 0) {
                int rloc = wr * 128 + m * 16 + lr * 4 + q;
                red_m[wc * 256 + rloc] = mx;
                red_s[wc * 256 + rloc] = ss;
            }
            int rowg = rb * BM + wr * 128 + m * 16 + lr * 4 + q;
            if (rowg < N_) {
                int bb = rowg / (S_ - 1);
                int s = rowg - bb * (S_ - 1);
                int lbl = labels[bb * S_ + s + 1];
                int ccol = lbl - (vb * BN + wc * 64);
                if (ccol >= 0 && ccol < 64 && (ccol & 15) == lq) {
                    int nsel = ccol >> 4;
                    float val;
                    if (nsel == 0)      val = l0;
                    else if (nsel == 1) val = l1;
                    else if (nsel == 2) val = l2;
                    else                val = l3;
                    label_logit[rowg] = val;
                }
            }
        }
    }
    __syncthreads();
    if (tid < 256) {
        float m0 = red_m[tid], m1 = red_m[256 + tid], m2 = red_m[512 + tid], m3 = red_m[768 + tid];
        float s0 = red_s[tid], s1 = red_s[256 + tid], s2 = red_s[512 + tid], s3 = red_s[768 + tid];
        float mm = fmaxf(fmaxf(m0, m1), fmaxf(m2, m3));
        float ss = s0 * __expf(m0 - mm) + s1 * __expf(m1 - mm)
                 + s2 * __expf(m2 - mm) + s3 * __expf(m3 - mm);
        int rowg = rb * BM + tid;
        partial_m[(size_t)rowg * NVB + vb] = mm;
        partial_s[(size_t)rowg * NVB + vb] = ss;
    }
}

// ---------- per-row combine of partials -> nll ----------
__global__ void row_nll_kernel(const float* __restrict__ partial_m,
                               const float* __restrict__ partial_s,
                               const float* __restrict__ label_logit,
                               const int* __restrict__ labels,
                               float* __restrict__ nll)
{
    int row = blockIdx.x * blockDim.x + threadIdx.x;
    if (row >= N_) return;
    const float* pm = partial_m + (size_t)row * NVB;
    const float* ps = partial_s + (size_t)row * NVB;
    float mm = -INFINITY;
    for (int j = 0; j < NVB; ++j) mm = fmaxf(mm, pm[j]);
    float ss = 0.f;
    for (int j = 0; j < NVB; ++j) ss += ps[j] * expf(pm[j] - mm);
    float lse = mm + logf(ss);
    int b = row / (S_ - 1);
    int s = row - b * (S_ - 1);
    int lbl = labels[b * S_ + s + 1];
    float out = 0.f;
    if (lbl != IGNORE_INDEX) out = lse - label_logit[row];
    nll[row] = out;
}

// ---------- final mean over valid rows ----------
__global__ void final_reduce_kernel(const float* __restrict__ nll,
                                    const int* __restrict__ labels,
                                    float* __restrict__ out)
{
    __shared__ float s_sum[256];
    __shared__ float s_cnt[256];
    int tid = threadIdx.x;
    float sum = 0.f, cnt = 0.f;
    for (int row = tid; row < N_; row += 256) {
        int b = row / (S_ - 1);
        int s = row - b * (S_ - 1);
        int lbl = labels[b * S_ + s + 1];
        if (lbl != IGNORE_INDEX) { sum += nll[row]; cnt += 1.f; }
    }
    s_sum[tid] = sum; s_cnt[tid] = cnt;
    __syncthreads();
    for (int d = 128; d > 0; d >>= 1) {
        if (tid < d) { s_sum[tid] += s_sum[tid + d]; s_cnt[tid] += s_cnt[tid + d]; }
        __syncthreads();
    }
    if (tid == 0) out[0] = s_sum[0] / fmaxf(s_cnt[0], 1.f);
}

extern "C" void kernel_launch(void* const* d_in, const int* in_sizes, int n_in,
                              void* d_out, int out_size, void* d_ws, size_t ws_size,
                              hipStream_t stream) {
    const float* hs  = (const float*)d_in[0];
    const float* w   = (const float*)d_in[1];
    const int*   lbl = (const int*)d_in[2];
    float* out = (float*)d_out;

    char* ws = (char*)d_ws;
    size_t off = 0;
    signed char* qA = (signed char*)(ws + off); off += (size_t)NPAD * H_;      // 33.5 MB
    signed char* qW = (signed char*)(ws + off); off += (size_t)V_ * H_;        // 131 MB
    float* sA          = (float*)(ws + off); off += (size_t)NPAD * 4;
    float* sW          = (float*)(ws + off); off += (size_t)V_ * 4;
    float* partial_m   = (float*)(ws + off); off += (size_t)NPAD * NVB * 4;    // 4 MB
    float* partial_s   = (float*)(ws + off); off += (size_t)NPAD * NVB * 4;    // 4 MB
    float* label_logit = (float*)(ws + off); off += (size_t)NPAD * 4;
    float* nll         = (float*)(ws + off); off += (size_t)NPAD * 4;

    quant_hs_kernel<<<NPAD, 256, 0, stream>>>(hs, qA, sA);
    quant_w_kernel<<<V_, 256, 0, stream>>>(w, qW, sW);
    gemm_lse_kernel<<<NWG, 512, 0, stream>>>(qA, qW, sA, sW, lbl,
                                             partial_m, partial_s, label_logit);
    row_nll_kernel<<<(N_ + 255) / 256, 256, 0, stream>>>(partial_m, partial_s, label_logit, lbl, nll);
    final_reduce_kernel<<<1, 256, 0, stream>>>(nll, lbl, out);
}

// Round 9
// 1250.734 us; speedup vs baseline: 1.4003x; 1.4003x over previous
//
#include <hip/hip_runtime.h>
#include <math.h>

#define IGNORE_INDEX (-100)

typedef __attribute__((ext_vector_type(4))) int i32x4;
typedef __attribute__((ext_vector_type(4))) float f32x4;

static constexpr int B_ = 4, S_ = 2048, H_ = 4096, V_ = 32000;
static constexpr int N_ = B_ * (S_ - 1);      // 8188 rows after causal shift
static constexpr int NPAD = 8192;             // padded rows
static constexpr int BM = 256, BN = 256, BK = 128;
static constexpr int NVB = V_ / BN;           // 125 v-blocks
static constexpr int NRB = NPAD / BM;         // 32 row-blocks
static constexpr int NKT = H_ / BK;           // 32 K-tiles
static constexpr int NWG = NVB * NRB;         // 4000 blocks

__device__ __forceinline__ void gload16(const signed char* src, signed char* ldst) {
    __builtin_amdgcn_global_load_lds(
        (const __attribute__((address_space(1))) unsigned int*)src,
        (__attribute__((address_space(3))) unsigned int*)ldst, 16, 0, 0);
}

// ---------- per-row symmetric int8 quantization of hidden_states (causal-shifted, padded) ----------
__global__ void quant_hs_kernel(const float* __restrict__ hs,
                                signed char* __restrict__ qA, float* __restrict__ sA) {
    const int row = blockIdx.x;          // 0..NPAD-1
    const int tid = threadIdx.x;         // 256 threads
    __shared__ float red[256];
    f32x4 v0, v1, v2, v3;
    if (row < N_) {
        int b = row / (S_ - 1);
        int s = row - b * (S_ - 1);
        const float* src = hs + (size_t)(b * S_ + s) * H_;
        v0 = *(const f32x4*)(src + tid * 4 + 0 * 1024);
        v1 = *(const f32x4*)(src + tid * 4 + 1 * 1024);
        v2 = *(const f32x4*)(src + tid * 4 + 2 * 1024);
        v3 = *(const f32x4*)(src + tid * 4 + 3 * 1024);
    } else {
        v0 = v1 = v2 = v3 = (f32x4)0.f;
    }
    float amax = 0.f;
    amax = fmaxf(amax, fmaxf(fmaxf(fabsf(v0[0]), fabsf(v0[1])), fmaxf(fabsf(v0[2]), fabsf(v0[3]))));
    amax = fmaxf(amax, fmaxf(fmaxf(fabsf(v1[0]), fabsf(v1[1])), fmaxf(fabsf(v1[2]), fabsf(v1[3]))));
    amax = fmaxf(amax, fmaxf(fmaxf(fabsf(v2[0]), fabsf(v2[1])), fmaxf(fabsf(v2[2]), fabsf(v2[3]))));
    amax = fmaxf(amax, fmaxf(fmaxf(fabsf(v3[0]), fabsf(v3[1])), fmaxf(fabsf(v3[2]), fabsf(v3[3]))));
    red[tid] = amax;
    __syncthreads();
    for (int d = 128; d > 0; d >>= 1) {
        if (tid < d) red[tid] = fmaxf(red[tid], red[tid + d]);
        __syncthreads();
    }
    const float m = fmaxf(red[0], 1e-30f);
    const float inv = 127.f / m;
    unsigned int* dst = (unsigned int*)(qA + (size_t)row * H_);
#define QPACK(vv, J) do { \
    int q0 = __float2int_rn(vv[0] * inv), q1 = __float2int_rn(vv[1] * inv); \
    int q2 = __float2int_rn(vv[2] * inv), q3 = __float2int_rn(vv[3] * inv); \
    unsigned int p = (q0 & 255) | ((q1 & 255) << 8) | ((q2 & 255) << 16) | ((unsigned)(q3 & 255) << 24); \
    dst[tid + (J) * 256] = p; } while (0)
    QPACK(v0, 0); QPACK(v1, 1); QPACK(v2, 2); QPACK(v3, 3);
#undef QPACK
    if (tid == 0) sA[row] = m * (1.f / 127.f);
}

// ---------- per-row symmetric int8 quantization of lm_head weight ----------
__global__ void quant_w_kernel(const float* __restrict__ w,
                               signed char* __restrict__ qW, float* __restrict__ sW) {
    const int row = blockIdx.x;          // 0..V-1
    const int tid = threadIdx.x;
    __shared__ float red[256];
    const float* src = w + (size_t)row * H_;
    f32x4 v0 = *(const f32x4*)(src + tid * 4 + 0 * 1024);
    f32x4 v1 = *(const f32x4*)(src + tid * 4 + 1 * 1024);
    f32x4 v2 = *(const f32x4*)(src + tid * 4 + 2 * 1024);
    f32x4 v3 = *(const f32x4*)(src + tid * 4 + 3 * 1024);
    float amax = 0.f;
    amax = fmaxf(amax, fmaxf(fmaxf(fabsf(v0[0]), fabsf(v0[1])), fmaxf(fabsf(v0[2]), fabsf(v0[3]))));
    amax = fmaxf(amax, fmaxf(fmaxf(fabsf(v1[0]), fabsf(v1[1])), fmaxf(fabsf(v1[2]), fabsf(v1[3]))));
    amax = fmaxf(amax, fmaxf(fmaxf(fabsf(v2[0]), fabsf(v2[1])), fmaxf(fabsf(v2[2]), fabsf(v2[3]))));
    amax = fmaxf(amax, fmaxf(fmaxf(fabsf(v3[0]), fabsf(v3[1])), fmaxf(fabsf(v3[2]), fabsf(v3[3]))));
    red[tid] = amax;
    __syncthreads();
    for (int d = 128; d > 0; d >>= 1) {
        if (tid < d) red[tid] = fmaxf(red[tid], red[tid + d]);
        __syncthreads();
    }
    const float m = fmaxf(red[0], 1e-30f);
    const float inv = 127.f / m;
    unsigned int* dst = (unsigned int*)(qW + (size_t)row * H_);
#define QPACK(vv, J) do { \
    int q0 = __float2int_rn(vv[0] * inv), q1 = __float2int_rn(vv[1] * inv); \
    int q2 = __float2int_rn(vv[2] * inv), q3 = __float2int_rn(vv[3] * inv); \
    unsigned int p = (q0 & 255) | ((q1 & 255) << 8) | ((q2 & 255) << 16) | ((unsigned)(q3 & 255) << 24); \
    dst[tid + (J) * 256] = p; } while (0)
    QPACK(v0, 0); QPACK(v1, 1); QPACK(v2, 2); QPACK(v3, 3);
#undef QPACK
    if (tid == 0) sW[row] = m * (1.f / 127.f);
}

// ---------- 256x256 8-wave i8 GEMM (BK=128), minimal-barrier, compiler-scheduled interior ----------
// LDS layout identical to R7 (verified 0 bank conflicts): [256 rows][128 cols] i8,
// physical byte = r*128 + ((slot*16) ^ ((r&7)<<4)); kk half-step = phys^64; staging source
// inverse-swizzled.  THIS ROUND: the 8 mid-tile barriers are removed (no intra-tile
// inter-wave dependency exists — only the tile-boundary dbuf hazard needs a barrier).
// No setprio / sched_barrier / volatile / manual lgkmcnt: R4/R5/R8 showed hand scheduling
// is null-to-negative here; the compiler emits counted lgkmcnt for read->MFMA on its own,
// and un-phase-locked waves drift so one wave's MFMA burst covers the other's ds_reads
// (m114 co-scheduling, the mechanism behind m97's 912 TF).  One __syncthreads per tile
// (emits vmcnt(0) lgkmcnt(0) + s_barrier -> staged data landed, dbuf swap safe).
__global__ __launch_bounds__(512, 2) void gemm_lse_kernel(
        const signed char* __restrict__ Aq,    // [NPAD][H] i8
        const signed char* __restrict__ Wq,    // [V][H] i8
        const float* __restrict__ sA,          // [NPAD]
        const float* __restrict__ sW,          // [V]
        const int* __restrict__ labels,        // [B][S]
        float* __restrict__ partial_m,         // [NPAD][NVB]
        float* __restrict__ partial_s,         // [NPAD][NVB]
        float* __restrict__ label_logit)       // [NPAD]
{
    __shared__ signed char lds[2][2][BM * BK];   // [buf][A=0/B=1], 2 x 64 KiB = 128 KiB

    const int tid  = threadIdx.x;
    const int lane = tid & 63;
    const int wid  = tid >> 6;
    const int wr   = wid >> 2;      // 0..1: row half
    const int wc   = wid & 3;       // 0..3: col quarter
    const int lq   = lane & 15;
    const int lr   = lane >> 4;

    // bijective XCD swizzle (NWG % 8 == 0)
    int lin = blockIdx.x;
    int swz = (lin & 7) * (NWG / 8) + (lin >> 3);
    const int rb = swz / NVB;
    const int vb = swz - rb * NVB;

    const signed char* Abase = Aq + (size_t)rb * BM * H_;
    const signed char* Bbase = Wq + (size_t)vb * BN * H_;

    // ds_read physical byte offsets for kk=0 (kk=1 is offset ^ 64)
    int pA[8], pB[4];
    #pragma unroll
    for (int m = 0; m < 8; ++m) {
        int r = wr * 128 + m * 16 + lq;
        pA[m] = r * 128 + ((lr * 16) ^ ((r & 7) << 4));
    }
    #pragma unroll
    for (int n = 0; n < 4; ++n) {
        int r = wc * 64 + n * 16 + lq;
        pB[n] = r * 128 + ((lr * 16) ^ ((r & 7) << 4));
    }

    // staging: linear physical dest (gload_lds = base + lane*16); inverse-swizzled source.
    int rowS[4], colS[4];
    #pragma unroll
    for (int i = 0; i < 4; ++i) {
        int q = i * 8192 + wid * 1024 + lane * 16;   // physical
        int b = q ^ (((q >> 7) & 7) << 4);           // logical
        rowS[i] = b >> 7;
        colS[i] = b & 127;                           // i8: byte == element
    }

    i32x4 acc[8][4] = {};

    // ---------- prologue: stage K-tile 0 into buf 0 ----------
    {
        signed char* dA = &lds[0][0][0];
        signed char* dB = &lds[0][1][0];
        #pragma unroll
        for (int i = 0; i < 4; ++i)
            gload16(Abase + (size_t)rowS[i] * H_ + colS[i], dA + i * 8192 + wid * 1024);
        #pragma unroll
        for (int i = 0; i < 4; ++i)
            gload16(Bbase + (size_t)rowS[i] * H_ + colS[i], dB + i * 8192 + wid * 1024);
    }
    __syncthreads();

#define RDI(tile, off) (*(const i32x4*)((const char*)(tile) + (off)))
#define MF(af, bf, c4) __builtin_amdgcn_mfma_i32_16x16x64_i8(af, bf, c4, 0, 0, 0)

    for (int T = 0; T < NKT; ++T) {
        const int cur = T & 1;
        const signed char* tA = &lds[cur][0][0];
        const signed char* tB = &lds[cur][1][0];
        signed char* dA = &lds[cur ^ 1][0][0];
        signed char* dB = &lds[cur ^ 1][1][0];
        const int kn = (T + 1) * BK;

        // issue next tile's staging first (HBM latency hides under this tile's compute)
        if (T + 1 < NKT) {
            #pragma unroll
            for (int i = 0; i < 4; ++i)
                gload16(Abase + (size_t)rowS[i] * H_ + kn + colS[i], dA + i * 8192 + wid * 1024);
            #pragma unroll
            for (int i = 0; i < 4; ++i)
                gload16(Bbase + (size_t)rowS[i] * H_ + kn + colS[i], dB + i * 8192 + wid * 1024);
        }

        // compiler-scheduled interior: 24 ds_read_b128 + 64 MFMA, no manual ordering
        #pragma unroll
        for (int kk = 0; kk < 128; kk += 64) {
            i32x4 av[8], bv[4];
            #pragma unroll
            for (int m = 0; m < 8; ++m) av[m] = RDI(tA, pA[m] ^ kk);
            #pragma unroll
            for (int n = 0; n < 4; ++n) bv[n] = RDI(tB, pB[n] ^ kk);
            #pragma unroll
            for (int m = 0; m < 8; ++m)
                #pragma unroll
                for (int n = 0; n < 4; ++n)
                    acc[m][n] = MF(av[m], bv[n], acc[m][n]);
        }

        // single tile-boundary barrier: drains staging (vmcnt) and syncs dbuf swap
        __syncthreads();
    }

    // ---------- epilogue: dequant + per-row max & sum-exp over this 256-col tile ----------
    float* red_m = (float*)&lds[0][0][0];   // [4][256]
    float* red_s = red_m + 1024;            // [4][256]

    const float* sArow = sA + rb * 256 + wr * 128;
    const float sw0 = sW[vb * 256 + wc * 64 + 0 * 16 + lq];
    const float sw1 = sW[vb * 256 + wc * 64 + 1 * 16 + lq];
    const float sw2 = sW[vb * 256 + wc * 64 + 2 * 16 + lq];
    const float sw3 = sW[vb * 256 + wc * 64 + 3 * 16 + lq];

    #pragma unroll
    for (int m = 0; m < 8; ++m) {
        f32x4 sav = *(const f32x4*)(sArow + m * 16 + lr * 4);
        #pragma unroll
        for (int q = 0; q < 4; ++q) {
            const float sa = sav[q];
            float l0 = (float)acc[m][0][q] * sa * sw0;
            float l1 = (float)acc[m][1][q] * sa * sw1;
            float l2 = (float)acc[m][2][q] * sa * sw2;
            float l3 = (float)acc[m][3][q] * sa * sw3;
            float mx = fmaxf(fmaxf(l0, l1), fmaxf(l2, l3));
            #pragma unroll
            for (int d = 1; d < 16; d <<= 1) mx = fmaxf(mx, __shfl_xor(mx, d, 64));
            float ss = __expf(l0 - mx) + __expf(l1 - mx) + __expf(l2 - mx) + __expf(l3 - mx);
            #pragma unroll
            for (int d = 1; d < 16; d <<= 1) ss += __shfl_xor(ss, d, 64);
            if (lq == 0) {
                int rloc = wr * 128 + m * 16 + lr * 4 + q;
                red_m[wc * 256 + rloc] = mx;
                red_s[wc * 256 + rloc] = ss;
            }
            int rowg = rb * BM + wr * 128 + m * 16 + lr * 4 + q;
            if (rowg < N_) {
                int bb = rowg / (S_ - 1);
                int s = rowg - bb * (S_ - 1);
                int lbl = labels[bb * S_ + s + 1];
                int ccol = lbl - (vb * BN + wc * 64);
                if (ccol >= 0 && ccol < 64 && (ccol & 15) == lq) {
                    int nsel = ccol >> 4;
                    float val;
                    if (nsel == 0)      val = l0;
                    else if (nsel == 1) val = l1;
                    else if (nsel == 2) val = l2;
                    else                val = l3;
                    label_logit[rowg] = val;
                }
            }
        }
    }
    __syncthreads();
    if (tid < 256) {
        float m0 = red_m[tid], m1 = red_m[256 + tid], m2 = red_m[512 + tid], m3 = red_m[768 + tid];
        float s0 = red_s[tid], s1 = red_s[256 + tid], s2 = red_s[512 + tid], s3 = red_s[768 + tid];
        float mm = fmaxf(fmaxf(m0, m1), fmaxf(m2, m3));
        float ss = s0 * __expf(m0 - mm) + s1 * __expf(m1 - mm)
                 + s2 * __expf(m2 - mm) + s3 * __expf(m3 - mm);
        int rowg = rb * BM + tid;
        partial_m[(size_t)rowg * NVB + vb] = mm;
        partial_s[(size_t)rowg * NVB + vb] = ss;
    }
}

// ---------- per-row combine of partials -> nll ----------
__global__ void row_nll_kernel(const float* __restrict__ partial_m,
                               const float* __restrict__ partial_s,
                               const float* __restrict__ label_logit,
                               const int* __restrict__ labels,
                               float* __restrict__ nll)
{
    int row = blockIdx.x * blockDim.x + threadIdx.x;
    if (row >= N_) return;
    const float* pm = partial_m + (size_t)row * NVB;
    const float* ps = partial_s + (size_t)row * NVB;
    float mm = -INFINITY;
    for (int j = 0; j < NVB; ++j) mm = fmaxf(mm, pm[j]);
    float ss = 0.f;
    for (int j = 0; j < NVB; ++j) ss += ps[j] * expf(pm[j] - mm);
    float lse = mm + logf(ss);
    int b = row / (S_ - 1);
    int s = row - b * (S_ - 1);
    int lbl = labels[b * S_ + s + 1];
    float out = 0.f;
    if (lbl != IGNORE_INDEX) out = lse - label_logit[row];
    nll[row] = out;
}

// ---------- final mean over valid rows ----------
__global__ void final_reduce_kernel(const float* __restrict__ nll,
                                    const int* __restrict__ labels,
                                    float* __restrict__ out)
{
    __shared__ float s_sum[256];
    __shared__ float s_cnt[256];
    int tid = threadIdx.x;
    float sum = 0.f, cnt = 0.f;
    for (int row = tid; row < N_; row += 256) {
        int b = row / (S_ - 1);
        int s = row - b * (S_ - 1);
        int lbl = labels[b * S_ + s + 1];
        if (lbl != IGNORE_INDEX) { sum += nll[row]; cnt += 1.f; }
    }
    s_sum[tid] = sum; s_cnt[tid] = cnt;
    __syncthreads();
    for (int d = 128; d > 0; d >>= 1) {
        if (tid < d) { s_sum[tid] += s_sum[tid + d]; s_cnt[tid] += s_cnt[tid + d]; }
        __syncthreads();
    }
    if (tid == 0) out[0] = s_sum[0] / fmaxf(s_cnt[0], 1.f);
}

extern "C" void kernel_launch(void* const* d_in, const int* in_sizes, int n_in,
                              void* d_out, int out_size, void* d_ws, size_t ws_size,
                              hipStream_t stream) {
    const float* hs  = (const float*)d_in[0];
    const float* w   = (const float*)d_in[1];
    const int*   lbl = (const int*)d_in[2];
    float* out = (float*)d_out;

    char* ws = (char*)d_ws;
    size_t off = 0;
    signed char* qA = (signed char*)(ws + off); off += (size_t)NPAD * H_;      // 33.5 MB
    signed char* qW = (signed char*)(ws + off); off += (size_t)V_ * H_;        // 131 MB
    float* sA          = (float*)(ws + off); off += (size_t)NPAD * 4;
    float* sW          = (float*)(ws + off); off += (size_t)V_ * 4;
    float* partial_m   = (float*)(ws + off); off += (size_t)NPAD * NVB * 4;    // 4 MB
    float* partial_s   = (float*)(ws + off); off += (size_t)NPAD * NVB * 4;    // 4 MB
    float* label_logit = (float*)(ws + off); off += (size_t)NPAD * 4;
    float* nll         = (float*)(ws + off); off += (size_t)NPAD * 4;

    quant_hs_kernel<<<NPAD, 256, 0, stream>>>(hs, qA, sA);
    quant_w_kernel<<<V_, 256, 0, stream>>>(w, qW, sW);
    gemm_lse_kernel<<<NWG, 512, 0, stream>>>(qA, qW, sA, sW, lbl,
                                             partial_m, partial_s, label_logit);
    row_nll_kernel<<<(N_ + 255) / 256, 256, 0, stream>>>(partial_m, partial_s, label_logit, lbl, nll);
    final_reduce_kernel<<<1, 256, 0, stream>>>(nll, lbl, out);
}